// Round 1
// baseline (1709.152 us; speedup 1.0000x reference)
//
#include <hip/hip_runtime.h>
#include <hip/hip_cooperative_groups.h>
#include <cfloat>
#include <cmath>

namespace cg = cooperative_groups;

#define N_Q 4096
#define N_S 1600
#define DIM 1024
#define N_C 64
#define KNN 12
#define MAX_ITER 50
#define EPS_CONV 1e-4f

__device__ __forceinline__ float wave_max64(float v){
  #pragma unroll
  for (int o = 32; o; o >>= 1) v = fmaxf(v, __shfl_xor(v, o, 64));
  return v;
}
__device__ __forceinline__ float wave_sum64(float v){
  #pragma unroll
  for (int o = 32; o; o >>= 1) v += __shfl_xor(v, o, 64);
  return v;
}
__device__ __forceinline__ float wave_min64(float v){
  #pragma unroll
  for (int o = 32; o; o >>= 1) v = fminf(v, __shfl_xor(v, o, 64));
  return v;
}

// ---- prototypes: segment mean over support set, stored TRANSPOSED Pt[f][c];
//      also per-class squared norm pn[c]. Summation in sample-index order
//      (matches segment_sum accumulation order).
__global__ __launch_bounds__(256) void proto_kernel(
    const float* __restrict__ fs, const int* __restrict__ ys,
    float* __restrict__ Pt, float* __restrict__ pn)
{
  const int c = blockIdx.x, t = threadIdx.x;
  float a0 = 0.f, a1 = 0.f, a2 = 0.f, a3 = 0.f;
  int cnt = 0;
  for (int i = 0; i < N_S; i++){
    if (ys[i] == c){
      const float* r = fs + (size_t)i * DIM;
      a0 += r[t]; a1 += r[t + 256]; a2 += r[t + 512]; a3 += r[t + 768];
      cnt++;
    }
  }
  const float inv = 1.0f / fmaxf((float)cnt, 1.0f);
  const float v0 = a0*inv, v1 = a1*inv, v2 = a2*inv, v3 = a3*inv;
  Pt[(t      )*N_C + c] = v0;
  Pt[(t + 256)*N_C + c] = v1;
  Pt[(t + 512)*N_C + c] = v2;
  Pt[(t + 768)*N_C + c] = v3;
  __shared__ float red[256];
  red[t] = v0*v0 + v1*v1 + v2*v2 + v3*v3;
  __syncthreads();
  for (int o = 128; o; o >>= 1){ if (t < o) red[t] += red[t + o]; __syncthreads(); }
  if (t == 0) pn[c] = red[0];
}

// ---- per-row squared norm of feat_q
__global__ __launch_bounds__(256) void rownorm_kernel(
    const float* __restrict__ X, float* __restrict__ qn)
{
  const int i = blockIdx.x, t = threadIdx.x;
  const float* r = X + (size_t)i * DIM;
  float s = r[t]*r[t] + r[t+256]*r[t+256] + r[t+512]*r[t+512] + r[t+768]*r[t+768];
  __shared__ float red[256];
  red[t] = s; __syncthreads();
  for (int o = 128; o; o >>= 1){ if (t < o) red[t] += red[t + o]; __syncthreads(); }
  if (t == 0) qn[i] = red[0];
}

// ---- full pairwise distance matrix: D = sqrt(max(qn_i + qn_j - 2 x_i.x_j, 0))
//      classic 128x128 tile SGEMM, 256 threads, 8x8 per thread, BK=8
__global__ __launch_bounds__(256) void dist_gemm(
    const float* __restrict__ X, const float* __restrict__ qn, float* __restrict__ Dq)
{
  __shared__ float As[8][128];
  __shared__ float Bs[8][128];
  const int t  = threadIdx.x;
  const int tx = t & 15, ty = t >> 4;
  const int i0 = blockIdx.y * 128, j0 = blockIdx.x * 128;
  const int lr = t >> 1, lh = (t & 1) * 4;
  float acc[8][8];
  #pragma unroll
  for (int u = 0; u < 8; u++)
    #pragma unroll
    for (int v = 0; v < 8; v++) acc[u][v] = 0.f;

  for (int k0 = 0; k0 < DIM; k0 += 8){
    float4 av = *(const float4*)(X + (size_t)(i0 + lr) * DIM + k0 + lh);
    float4 bv = *(const float4*)(X + (size_t)(j0 + lr) * DIM + k0 + lh);
    As[lh+0][lr] = av.x; As[lh+1][lr] = av.y; As[lh+2][lr] = av.z; As[lh+3][lr] = av.w;
    Bs[lh+0][lr] = bv.x; Bs[lh+1][lr] = bv.y; Bs[lh+2][lr] = bv.z; Bs[lh+3][lr] = bv.w;
    __syncthreads();
    #pragma unroll
    for (int k = 0; k < 8; k++){
      float a[8], b[8];
      #pragma unroll
      for (int u = 0; u < 8; u++) a[u] = As[k][ty*8 + u];
      #pragma unroll
      for (int v = 0; v < 8; v++) b[v] = Bs[k][tx*8 + v];
      #pragma unroll
      for (int u = 0; u < 8; u++)
        #pragma unroll
        for (int v = 0; v < 8; v++) acc[u][v] = fmaf(a[u], b[v], acc[u][v]);
    }
    __syncthreads();
  }
  #pragma unroll
  for (int u = 0; u < 8; u++){
    const int i = i0 + ty*8 + u;
    const float qi = qn[i];
    #pragma unroll
    for (int v = 0; v < 8; v++){
      const int j = j0 + tx*8 + v;
      float d2 = qi + qn[j] - 2.0f * acc[u][v];
      Dq[(size_t)i * N_Q + j] = sqrtf(fmaxf(d2, 0.f));
    }
  }
}

// ---- per-row 13 smallest distances (ties -> smaller index, like lax.top_k).
//      slot 0 ignored (self), slots 1..12 -> neighbors, slot 12 -> sigma.
__global__ __launch_bounds__(256) void topk_kernel(
    const float* __restrict__ Dq, int* __restrict__ nbr,
    float* __restrict__ dnbr, float* __restrict__ sigma)
{
  const int i = blockIdx.x, t = threadIdx.x;
  __shared__ float sv[N_Q];
  __shared__ float rv[256];
  __shared__ int   ri[256];
  const float* row = Dq + (size_t)i * N_Q;
  for (int j = t; j < N_Q; j += 256) sv[j] = row[j];
  __syncthreads();
  for (int s = 0; s < KNN + 1; s++){
    float best = FLT_MAX; int bidx = N_Q;
    for (int j = t; j < N_Q; j += 256){
      float v = sv[j];
      if (v < best){ best = v; bidx = j; }   // strict < keeps earliest index
    }
    rv[t] = best; ri[t] = bidx;
    __syncthreads();
    for (int o = 128; o; o >>= 1){
      if (t < o){
        float v2 = rv[t + o]; int i2 = ri[t + o];
        if (v2 < rv[t] || (v2 == rv[t] && i2 < ri[t])){ rv[t] = v2; ri[t] = i2; }
      }
      __syncthreads();
    }
    if (t == 0){
      int idx = ri[0];
      if (s >= 1){ nbr[i*KNN + s - 1] = idx; dnbr[i*KNN + s - 1] = rv[0]; }
      if (s == KNN) sigma[i] = rv[0] + 1e-8f;
      sv[idx] = FLT_MAX;
    }
    __syncthreads();
  }
}

// ---- a[i][c] = clamped sqdist(query i, proto c); d2min[i] = min_c a[i][c]
__global__ __launch_bounds__(64) void a_kernel(
    const float* __restrict__ Xq, const float* __restrict__ Pt,
    const float* __restrict__ qn, const float* __restrict__ pn,
    float* __restrict__ aM, float* __restrict__ d2min)
{
  const int i = blockIdx.x, c = threadIdx.x;
  __shared__ float x[DIM];
  const float* r = Xq + (size_t)i * DIM;
  for (int f = c; f < DIM; f += 64) x[f] = r[f];
  __syncthreads();
  float dot = 0.f;
  #pragma unroll 4
  for (int f = 0; f < DIM; f++) dot = fmaf(x[f], Pt[f*N_C + c], dot);
  float d2 = fmaxf(qn[i] + pn[c] - 2.0f * dot, 0.0f);
  aM[i*N_C + c] = d2;
  float m = wave_min64(d2);
  if (c == 0) d2min[i] = m;
}

// ---- median of d = sqrt(d2min) via single-block bitonic sort of 4096;
//      denom = 2*med^2 + 1e-8
__global__ __launch_bounds__(1024) void median_kernel(
    const float* __restrict__ d2min, float* __restrict__ denom)
{
  __shared__ float s[N_Q];
  const int t = threadIdx.x;
  for (int j = t; j < N_Q; j += 1024) s[j] = sqrtf(d2min[j]);
  __syncthreads();
  for (int ksz = 2; ksz <= N_Q; ksz <<= 1){
    for (int st = ksz >> 1; st > 0; st >>= 1){
      for (int i = t; i < N_Q; i += 1024){
        int j = i ^ st;
        if (j > i){
          float a = s[i], b = s[j];
          bool up = ((i & ksz) == 0);
          if (up ? (a > b) : (a < b)){ s[i] = b; s[j] = a; }
        }
      }
      __syncthreads();
    }
  }
  if (t == 0){
    float med = 0.5f * (s[N_Q/2 - 1] + s[N_Q/2]);
    denom[0] = 2.0f * med * med + 1e-8f;
  }
}

// ---- halved edge weights, symmetric row sums, in-degree counts
__global__ __launch_bounds__(256) void wdeg_kernel(
    const int* __restrict__ nbr, const float* __restrict__ dnbr,
    const float* __restrict__ sigma, float* __restrict__ wh,
    float* __restrict__ rowsum, int* __restrict__ indeg)
{
  const int e = blockIdx.x * 256 + threadIdx.x;
  if (e >= N_Q * KNN) return;
  const int i = e / KNN;
  const int j = nbr[e];
  float w = 0.5f * expf(-dnbr[e] / (sigma[i] * sigma[j]));
  wh[e] = w;
  atomicAdd(&rowsum[i], w);
  atomicAdd(&rowsum[j], w);
  atomicAdd(&indeg[j], 1);
}

// ---- CSR row pointers: deg[r] = 12 (out) + indeg[r] (in)
__global__ __launch_bounds__(256) void scan_kernel(
    const int* __restrict__ indeg, int* __restrict__ rowptr)
{
  __shared__ int part[256];
  const int t = threadIdx.x;
  const int base = t * 16;
  int loc[16];
  int lsum = 0;
  for (int u = 0; u < 16; u++){ loc[u] = lsum; lsum += indeg[base + u]; }
  part[t] = lsum; __syncthreads();
  if (t == 0){
    int run = 0;
    for (int q = 0; q < 256; q++){ int v = part[q]; part[q] = run; run += v; }
  }
  __syncthreads();
  const int off = part[t];
  for (int u = 0; u < 16; u++){
    int r = base + u;
    rowptr[r] = KNN * r + off + loc[u];
  }
  if (t == 255) rowptr[N_Q] = KNN * N_Q + off + lsum;
}

// ---- CSR fill: out-edges in fixed slots, in-edges via per-row atomic cursor
__global__ __launch_bounds__(256) void fill_kernel(
    const int* __restrict__ nbr, const float* __restrict__ wh,
    const int* __restrict__ rowptr, int* __restrict__ fillc,
    int* __restrict__ colA, float* __restrict__ wAr)
{
  const int e = blockIdx.x * 256 + threadIdx.x;
  if (e >= N_Q * KNN) return;
  const int i = e / KNN, tt = e % KNN;
  const int j = nbr[e];
  const float w = wh[e];
  int p = rowptr[i] + tt;
  colA[p] = j; wAr[p] = w;
  int q = rowptr[j] + KNN + atomicAdd(&fillc[j], 1);
  colA[q] = i; wAr[q] = w;
}

// ---- coef[i] = lam_i * D_inv_i
__global__ __launch_bounds__(256) void coef_kernel(
    const float* __restrict__ d2min, const float* __restrict__ denom,
    const float* __restrict__ rowsum, float* __restrict__ coefA)
{
  const int i = blockIdx.x * 256 + threadIdx.x;
  if (i < N_Q){
    float lam = expf(-d2min[i] / denom[0]);
    coefA[i] = lam / (rowsum[i] + 1e-8f);
  }
}

// ---- the full while-loop as one cooperative kernel; wave-per-row, lane=class.
//      State (y, y_new) per element in registers; global ping-pong buffers carry
//      y_new across rows for the SpMV. Exact reference loop semantics:
//      while (i < 50 && max|y_new - y| >= 1e-4) { y = y_new; y_new = step(y_new); }
//      output = argmax(y).
__global__ __launch_bounds__(256, 4) void mm_loop(
    const float* __restrict__ aM, const float* __restrict__ coefA,
    const int* __restrict__ rowptr, const int* __restrict__ colA,
    const float* __restrict__ wA, float* __restrict__ buf0,
    float* __restrict__ buf1, float* deltas, int* __restrict__ out)
{
  cg::grid_group grid = cg::this_grid();
  const int lane = threadIdx.x & 63;
  const int row  = blockIdx.x * 4 + (threadIdx.x >> 6);
  const float av = aM[row * N_C + lane];
  const float cf = coefA[row];
  const int p0 = rowptr[row], p1 = rowptr[row + 1];

  // y0 = softmax(-a)
  float xv = -av;
  float m = wave_max64(xv);
  float e = expf(xv - m);
  float s = wave_sum64(e);
  float prev = e / s;                      // state y
  buf0[row * N_C + lane] = prev;
  grid.sync();

  // y1 = step(y0)
  float sp = 0.f;
  for (int p = p0; p < p1; p++) sp = fmaf(wA[p], buf0[colA[p] * N_C + lane], sp);
  xv = -av + cf * sp;
  m = wave_max64(xv); e = expf(xv - m); s = wave_sum64(e);
  float cur = e / s;                       // state y_new
  buf1[row * N_C + lane] = cur;
  float dm = wave_max64(fabsf(cur - prev));
  if (lane == 0) atomicMax((int*)&deltas[0], __float_as_int(dm));
  grid.sync();

  int par = 1;                             // buffer currently holding y_new
  for (int t = 0;; t++){
    float delta = __int_as_float(((volatile int*)deltas)[t]);
    if (t >= MAX_ITER || delta < EPS_CONV) break;
    const float* src = par ? buf1 : buf0;
    float*       dst = par ? buf0 : buf1;
    sp = 0.f;
    for (int p = p0; p < p1; p++) sp = fmaf(wA[p], src[colA[p] * N_C + lane], sp);
    xv = -av + cf * sp;
    m = wave_max64(xv); e = expf(xv - m); s = wave_sum64(e);
    float nxt = e / s;
    dst[row * N_C + lane] = nxt;
    dm = wave_max64(fabsf(nxt - cur));
    if (lane == 0) atomicMax((int*)&deltas[t + 1], __float_as_int(dm));
    prev = cur; cur = nxt; par ^= 1;
    grid.sync();
  }

  // argmax of y (prev); first occurrence on ties
  float bv = prev; int bi = lane;
  #pragma unroll
  for (int o = 32; o; o >>= 1){
    float ov = __shfl_xor(bv, o, 64); int oi = __shfl_xor(bi, o, 64);
    if (ov > bv || (ov == bv && oi < bi)){ bv = ov; bi = oi; }
  }
  if (lane == 0) out[row] = bi;
}

extern "C" void kernel_launch(void* const* d_in, const int* in_sizes, int n_in,
                              void* d_out, int out_size, void* d_ws, size_t ws_size,
                              hipStream_t stream)
{
  const float* feat_s = (const float*)d_in[0];
  const int*   y_s    = (const int*)d_in[1];
  const float* feat_q = (const float*)d_in[2];
  int* out = (int*)d_out;

  char* wp = (char*)d_ws;
  auto alloc = [&](size_t bytes) -> char* {
    char* p = wp;
    wp += (bytes + 255) & ~(size_t)255;
    return p;
  };
  float* Dq     = (float*)alloc((size_t)N_Q * N_Q * 4);      // 64 MB
  float* Pt     = (float*)alloc((size_t)DIM * N_C * 4);
  float* pn     = (float*)alloc(N_C * 4);
  float* qn     = (float*)alloc(N_Q * 4);
  float* aM     = (float*)alloc((size_t)N_Q * N_C * 4);
  float* d2min  = (float*)alloc(N_Q * 4);
  float* denom  = (float*)alloc(256);
  int*   nbr    = (int*)alloc((size_t)N_Q * KNN * 4);
  float* dnbr   = (float*)alloc((size_t)N_Q * KNN * 4);
  float* sigma  = (float*)alloc(N_Q * 4);
  float* wh     = (float*)alloc((size_t)N_Q * KNN * 4);
  float* rowsum = (float*)alloc(N_Q * 4);
  int*   indeg  = (int*)alloc(N_Q * 4);
  int*   rowptr = (int*)alloc((N_Q + 1) * 4);
  int*   fillc  = (int*)alloc(N_Q * 4);
  int*   colA   = (int*)alloc((size_t)2 * N_Q * KNN * 4);
  float* wA     = (float*)alloc((size_t)2 * N_Q * KNN * 4);
  float* buf0   = (float*)alloc((size_t)N_Q * N_C * 4);
  float* buf1   = (float*)alloc((size_t)N_Q * N_C * 4);
  float* deltas = (float*)alloc(64 * 4);
  float* coefA  = (float*)alloc(N_Q * 4);

  hipMemsetAsync(rowsum, 0, N_Q * 4, stream);
  hipMemsetAsync(indeg,  0, N_Q * 4, stream);
  hipMemsetAsync(fillc,  0, N_Q * 4, stream);
  hipMemsetAsync(deltas, 0, 64 * 4, stream);

  proto_kernel  <<<N_C, 256, 0, stream>>>(feat_s, y_s, Pt, pn);
  rownorm_kernel<<<N_Q, 256, 0, stream>>>(feat_q, qn);
  dist_gemm     <<<dim3(N_Q/128, N_Q/128), 256, 0, stream>>>(feat_q, qn, Dq);
  topk_kernel   <<<N_Q, 256, 0, stream>>>(Dq, nbr, dnbr, sigma);
  a_kernel      <<<N_Q, 64, 0, stream>>>(feat_q, Pt, qn, pn, aM, d2min);
  median_kernel <<<1, 1024, 0, stream>>>(d2min, denom);
  wdeg_kernel   <<<(N_Q*KNN + 255)/256, 256, 0, stream>>>(nbr, dnbr, sigma, wh, rowsum, indeg);
  scan_kernel   <<<1, 256, 0, stream>>>(indeg, rowptr);
  fill_kernel   <<<(N_Q*KNN + 255)/256, 256, 0, stream>>>(nbr, wh, rowptr, fillc, colA, wA);
  coef_kernel   <<<(N_Q + 255)/256, 256, 0, stream>>>(d2min, denom, rowsum, coefA);

  void* args[] = {&aM, &coefA, &rowptr, &colA, &wA, &buf0, &buf1, &deltas, &out};
  hipLaunchCooperativeKernel((void*)mm_loop, dim3(N_Q/4), dim3(256), args, 0, stream);
}

// Round 2
// 1318.339 us; speedup vs baseline: 1.2964x; 1.2964x over previous
//
#include <hip/hip_runtime.h>
#include <hip/hip_cooperative_groups.h>
#include <cfloat>
#include <cmath>

namespace cg = cooperative_groups;

#define N_Q 4096
#define N_S 1600
#define DIM 1024
#define N_C 64
#define KNN 12
#define MAX_ITER 50
#define EPS_CONV 1e-4f

__device__ __forceinline__ float wave_max64(float v){
  #pragma unroll
  for (int o = 32; o; o >>= 1) v = fmaxf(v, __shfl_xor(v, o, 64));
  return v;
}
__device__ __forceinline__ float wave_sum64(float v){
  #pragma unroll
  for (int o = 32; o; o >>= 1) v += __shfl_xor(v, o, 64);
  return v;
}
__device__ __forceinline__ float wave_min64(float v){
  #pragma unroll
  for (int o = 32; o; o >>= 1) v = fminf(v, __shfl_xor(v, o, 64));
  return v;
}

// ---- prototypes: segment mean over support set, stored TRANSPOSED Pt[f][c];
//      also per-class squared norm pn[c].
__global__ __launch_bounds__(256) void proto_kernel(
    const float* __restrict__ fs, const int* __restrict__ ys,
    float* __restrict__ Pt, float* __restrict__ pn)
{
  const int c = blockIdx.x, t = threadIdx.x;
  float a0 = 0.f, a1 = 0.f, a2 = 0.f, a3 = 0.f;
  int cnt = 0;
  for (int i = 0; i < N_S; i++){
    if (ys[i] == c){
      const float* r = fs + (size_t)i * DIM;
      a0 += r[t]; a1 += r[t + 256]; a2 += r[t + 512]; a3 += r[t + 768];
      cnt++;
    }
  }
  const float inv = 1.0f / fmaxf((float)cnt, 1.0f);
  const float v0 = a0*inv, v1 = a1*inv, v2 = a2*inv, v3 = a3*inv;
  Pt[(t      )*N_C + c] = v0;
  Pt[(t + 256)*N_C + c] = v1;
  Pt[(t + 512)*N_C + c] = v2;
  Pt[(t + 768)*N_C + c] = v3;
  __shared__ float red[256];
  red[t] = v0*v0 + v1*v1 + v2*v2 + v3*v3;
  __syncthreads();
  for (int o = 128; o; o >>= 1){ if (t < o) red[t] += red[t + o]; __syncthreads(); }
  if (t == 0) pn[c] = red[0];
}

// ---- per-row squared norm of feat_q
__global__ __launch_bounds__(256) void rownorm_kernel(
    const float* __restrict__ X, float* __restrict__ qn)
{
  const int i = blockIdx.x, t = threadIdx.x;
  const float* r = X + (size_t)i * DIM;
  float s = r[t]*r[t] + r[t+256]*r[t+256] + r[t+512]*r[t+512] + r[t+768]*r[t+768];
  __shared__ float red[256];
  red[t] = s; __syncthreads();
  for (int o = 128; o; o >>= 1){ if (t < o) red[t] += red[t + o]; __syncthreads(); }
  if (t == 0) qn[i] = red[0];
}

// ---- full pairwise distance matrix: D = sqrt(max(qn_i + qn_j - 2 x_i.x_j, 0))
//      128x128 tile, 256 threads. Waves in 2x2 grid (64x64 sub-tile each);
//      lane = 8x8 grid -> A/B LDS fragment reads are 8-distinct-float4 patterns
//      (2-way bank alias only, which is free on gfx950). Global loads for the
//      next K-tile are prefetched into registers across the compute phase.
__global__ __launch_bounds__(256, 4) void dist_gemm(
    const float* __restrict__ X, const float* __restrict__ qn, float* __restrict__ Dq)
{
  __shared__ float As[8][128];
  __shared__ float Bs[8][128];
  const int t = threadIdx.x;
  const int w = t >> 6, l = t & 63;
  const int ri = (w >> 1) * 64 + (l >> 3) * 8;   // row offset in tile
  const int cj = (w & 1) * 64 + (l & 7) * 8;     // col offset in tile
  const int i0 = blockIdx.y * 128, j0 = blockIdx.x * 128;
  const int lr = t >> 1, lh = (t & 1) * 4;

  const float* pA = X + (size_t)(i0 + lr) * DIM + lh;
  const float* pB = X + (size_t)(j0 + lr) * DIM + lh;

  float acc[8][8];
  #pragma unroll
  for (int u = 0; u < 8; u++)
    #pragma unroll
    for (int v = 0; v < 8; v++) acc[u][v] = 0.f;

  float4 ga = *(const float4*)pA;
  float4 gb = *(const float4*)pB;

  for (int k0 = 0; k0 < DIM; k0 += 8){
    As[lh+0][lr] = ga.x; As[lh+1][lr] = ga.y; As[lh+2][lr] = ga.z; As[lh+3][lr] = ga.w;
    Bs[lh+0][lr] = gb.x; Bs[lh+1][lr] = gb.y; Bs[lh+2][lr] = gb.z; Bs[lh+3][lr] = gb.w;
    __syncthreads();
    if (k0 + 8 < DIM){
      ga = *(const float4*)(pA + k0 + 8);
      gb = *(const float4*)(pB + k0 + 8);
    }
    #pragma unroll
    for (int k = 0; k < 8; k++){
      float4 a0 = *(const float4*)&As[k][ri];
      float4 a1 = *(const float4*)&As[k][ri + 4];
      float4 b0 = *(const float4*)&Bs[k][cj];
      float4 b1 = *(const float4*)&Bs[k][cj + 4];
      float a[8] = {a0.x,a0.y,a0.z,a0.w,a1.x,a1.y,a1.z,a1.w};
      float b[8] = {b0.x,b0.y,b0.z,b0.w,b1.x,b1.y,b1.z,b1.w};
      #pragma unroll
      for (int u = 0; u < 8; u++)
        #pragma unroll
        for (int v = 0; v < 8; v++) acc[u][v] = fmaf(a[u], b[v], acc[u][v]);
    }
    __syncthreads();
  }

  const float4 qj0 = *(const float4*)&qn[j0 + cj];
  const float4 qj1 = *(const float4*)&qn[j0 + cj + 4];
  const float qj[8] = {qj0.x,qj0.y,qj0.z,qj0.w,qj1.x,qj1.y,qj1.z,qj1.w};
  #pragma unroll
  for (int u = 0; u < 8; u++){
    const int i = i0 + ri + u;
    const float qi = qn[i];
    float o[8];
    #pragma unroll
    for (int v = 0; v < 8; v++)
      o[v] = sqrtf(fmaxf(qi + qj[v] - 2.0f * acc[u][v], 0.f));
    *(float4*)&Dq[(size_t)i * N_Q + j0 + cj    ] = make_float4(o[0],o[1],o[2],o[3]);
    *(float4*)&Dq[(size_t)i * N_Q + j0 + cj + 4] = make_float4(o[4],o[5],o[6],o[7]);
  }
}

// ---- per-row 13 smallest distances (ties -> smaller index, like lax.top_k).
__global__ __launch_bounds__(256) void topk_kernel(
    const float* __restrict__ Dq, int* __restrict__ nbr,
    float* __restrict__ dnbr, float* __restrict__ sigma)
{
  const int i = blockIdx.x, t = threadIdx.x;
  __shared__ float sv[N_Q];
  __shared__ float rv[256];
  __shared__ int   ri[256];
  const float* row = Dq + (size_t)i * N_Q;
  for (int j = t; j < N_Q; j += 256) sv[j] = row[j];
  __syncthreads();
  for (int s = 0; s < KNN + 1; s++){
    float best = FLT_MAX; int bidx = N_Q;
    for (int j = t; j < N_Q; j += 256){
      float v = sv[j];
      if (v < best){ best = v; bidx = j; }   // strict < keeps earliest index
    }
    rv[t] = best; ri[t] = bidx;
    __syncthreads();
    for (int o = 128; o; o >>= 1){
      if (t < o){
        float v2 = rv[t + o]; int i2 = ri[t + o];
        if (v2 < rv[t] || (v2 == rv[t] && i2 < ri[t])){ rv[t] = v2; ri[t] = i2; }
      }
      __syncthreads();
    }
    if (t == 0){
      int idx = ri[0];
      if (s >= 1){ nbr[i*KNN + s - 1] = idx; dnbr[i*KNN + s - 1] = rv[0]; }
      if (s == KNN) sigma[i] = rv[0] + 1e-8f;
      sv[idx] = FLT_MAX;
    }
    __syncthreads();
  }
}

// ---- a[i][c] = clamped sqdist(query i, proto c); d2min[i] = min_c a[i][c]
__global__ __launch_bounds__(64) void a_kernel(
    const float* __restrict__ Xq, const float* __restrict__ Pt,
    const float* __restrict__ qn, const float* __restrict__ pn,
    float* __restrict__ aM, float* __restrict__ d2min)
{
  const int i = blockIdx.x, c = threadIdx.x;
  __shared__ float x[DIM];
  const float* r = Xq + (size_t)i * DIM;
  for (int f = c; f < DIM; f += 64) x[f] = r[f];
  __syncthreads();
  float dot = 0.f;
  #pragma unroll 4
  for (int f = 0; f < DIM; f++) dot = fmaf(x[f], Pt[f*N_C + c], dot);
  float d2 = fmaxf(qn[i] + pn[c] - 2.0f * dot, 0.0f);
  aM[i*N_C + c] = d2;
  float m = wave_min64(d2);
  if (c == 0) d2min[i] = m;
}

// ---- median of d = sqrt(d2min) via single-block bitonic sort of 4096
__global__ __launch_bounds__(1024) void median_kernel(
    const float* __restrict__ d2min, float* __restrict__ denom)
{
  __shared__ float s[N_Q];
  const int t = threadIdx.x;
  for (int j = t; j < N_Q; j += 1024) s[j] = sqrtf(d2min[j]);
  __syncthreads();
  for (int ksz = 2; ksz <= N_Q; ksz <<= 1){
    for (int st = ksz >> 1; st > 0; st >>= 1){
      for (int i = t; i < N_Q; i += 1024){
        int j = i ^ st;
        if (j > i){
          float a = s[i], b = s[j];
          bool up = ((i & ksz) == 0);
          if (up ? (a > b) : (a < b)){ s[i] = b; s[j] = a; }
        }
      }
      __syncthreads();
    }
  }
  if (t == 0){
    float med = 0.5f * (s[N_Q/2 - 1] + s[N_Q/2]);
    denom[0] = 2.0f * med * med + 1e-8f;
  }
}

// ---- halved edge weights, symmetric row sums, in-degree counts
__global__ __launch_bounds__(256) void wdeg_kernel(
    const int* __restrict__ nbr, const float* __restrict__ dnbr,
    const float* __restrict__ sigma, float* __restrict__ wh,
    float* __restrict__ rowsum, int* __restrict__ indeg)
{
  const int e = blockIdx.x * 256 + threadIdx.x;
  if (e >= N_Q * KNN) return;
  const int i = e / KNN;
  const int j = nbr[e];
  float w = 0.5f * expf(-dnbr[e] / (sigma[i] * sigma[j]));
  wh[e] = w;
  atomicAdd(&rowsum[i], w);
  atomicAdd(&rowsum[j], w);
  atomicAdd(&indeg[j], 1);
}

// ---- CSR row pointers: deg[r] = 12 (out) + indeg[r] (in)
__global__ __launch_bounds__(256) void scan_kernel(
    const int* __restrict__ indeg, int* __restrict__ rowptr)
{
  __shared__ int part[256];
  const int t = threadIdx.x;
  const int base = t * 16;
  int loc[16];
  int lsum = 0;
  for (int u = 0; u < 16; u++){ loc[u] = lsum; lsum += indeg[base + u]; }
  part[t] = lsum; __syncthreads();
  if (t == 0){
    int run = 0;
    for (int q = 0; q < 256; q++){ int v = part[q]; part[q] = run; run += v; }
  }
  __syncthreads();
  const int off = part[t];
  for (int u = 0; u < 16; u++){
    int r = base + u;
    rowptr[r] = KNN * r + off + loc[u];
  }
  if (t == 255) rowptr[N_Q] = KNN * N_Q + off + lsum;
}

// ---- CSR fill: out-edges in fixed slots, in-edges via per-row atomic cursor
__global__ __launch_bounds__(256) void fill_kernel(
    const int* __restrict__ nbr, const float* __restrict__ wh,
    const int* __restrict__ rowptr, int* __restrict__ fillc,
    int* __restrict__ colA, float* __restrict__ wAr)
{
  const int e = blockIdx.x * 256 + threadIdx.x;
  if (e >= N_Q * KNN) return;
  const int i = e / KNN, tt = e % KNN;
  const int j = nbr[e];
  const float w = wh[e];
  int p = rowptr[i] + tt;
  colA[p] = j; wAr[p] = w;
  int q = rowptr[j] + KNN + atomicAdd(&fillc[j], 1);
  colA[q] = i; wAr[q] = w;
}

// ---- coef[i] = lam_i * D_inv_i
__global__ __launch_bounds__(256) void coef_kernel(
    const float* __restrict__ d2min, const float* __restrict__ denom,
    const float* __restrict__ rowsum, float* __restrict__ coefA)
{
  const int i = blockIdx.x * 256 + threadIdx.x;
  if (i < N_Q){
    float lam = expf(-d2min[i] / denom[0]);
    coefA[i] = lam / (rowsum[i] + 1e-8f);
  }
}

// ---- the while-loop as one cooperative kernel. 64 blocks x 1024 threads
//      (16 waves/block, 4 rows/wave) -- grid.sync cost scales with #blocks,
//      and at 1024 blocks it was 18 us/iter (R1 profile: VALUBusy 1.8%).
//      Exact reference loop semantics preserved.
__global__ __launch_bounds__(1024, 4) void mm_loop(
    const float* __restrict__ aM, const float* __restrict__ coefA,
    const int* __restrict__ rowptr, const int* __restrict__ colA,
    const float* __restrict__ wA, float* __restrict__ buf0,
    float* __restrict__ buf1, float* deltas, int* __restrict__ out)
{
  cg::grid_group grid = cg::this_grid();
  const int lane = threadIdx.x & 63;
  const int wid  = blockIdx.x * 16 + (threadIdx.x >> 6);
  const int rbase = wid * 4;

  float av[4], cf[4], prev[4], cur[4];
  int p0[4], p1[4];
  #pragma unroll
  for (int u = 0; u < 4; u++){
    const int row = rbase + u;
    av[u] = aM[row * N_C + lane];
    cf[u] = coefA[row];
    p0[u] = rowptr[row]; p1[u] = rowptr[row + 1];
  }

  // y0 = softmax(-a)
  #pragma unroll
  for (int u = 0; u < 4; u++){
    float xv = -av[u];
    float m = wave_max64(xv);
    float e = expf(xv - m);
    float s = wave_sum64(e);
    prev[u] = e / s;
    buf0[(rbase + u) * N_C + lane] = prev[u];
  }
  grid.sync();

  // y1 = step(y0)
  float dmax = 0.f;
  #pragma unroll
  for (int u = 0; u < 4; u++){
    float sp = 0.f;
    for (int p = p0[u]; p < p1[u]; p++) sp = fmaf(wA[p], buf0[colA[p] * N_C + lane], sp);
    float xv = -av[u] + cf[u] * sp;
    float m = wave_max64(xv);
    float e = expf(xv - m);
    float s = wave_sum64(e);
    cur[u] = e / s;
    buf1[(rbase + u) * N_C + lane] = cur[u];
    dmax = fmaxf(dmax, fabsf(cur[u] - prev[u]));
  }
  dmax = wave_max64(dmax);
  if (lane == 0) atomicMax((int*)&deltas[0], __float_as_int(dmax));
  grid.sync();

  int par = 1;                             // buffer currently holding y_new
  for (int t = 0;; t++){
    float delta = __int_as_float(((volatile int*)deltas)[t]);
    if (t >= MAX_ITER || delta < EPS_CONV) break;
    const float* src = par ? buf1 : buf0;
    float*       dst = par ? buf0 : buf1;
    dmax = 0.f;
    #pragma unroll
    for (int u = 0; u < 4; u++){
      float sp = 0.f;
      for (int p = p0[u]; p < p1[u]; p++) sp = fmaf(wA[p], src[colA[p] * N_C + lane], sp);
      float xv = -av[u] + cf[u] * sp;
      float m = wave_max64(xv);
      float e = expf(xv - m);
      float s = wave_sum64(e);
      float nxt = e / s;
      dst[(rbase + u) * N_C + lane] = nxt;
      dmax = fmaxf(dmax, fabsf(nxt - cur[u]));
      prev[u] = cur[u]; cur[u] = nxt;
    }
    dmax = wave_max64(dmax);
    if (lane == 0) atomicMax((int*)&deltas[t + 1], __float_as_int(dmax));
    par ^= 1;
    grid.sync();
  }

  // argmax of y (prev); first occurrence on ties
  #pragma unroll
  for (int u = 0; u < 4; u++){
    float bv = prev[u]; int bi = lane;
    #pragma unroll
    for (int o = 32; o; o >>= 1){
      float ov = __shfl_xor(bv, o, 64); int oi = __shfl_xor(bi, o, 64);
      if (ov > bv || (ov == bv && oi < bi)){ bv = ov; bi = oi; }
    }
    if (lane == 0) out[rbase + u] = bi;
  }
}

extern "C" void kernel_launch(void* const* d_in, const int* in_sizes, int n_in,
                              void* d_out, int out_size, void* d_ws, size_t ws_size,
                              hipStream_t stream)
{
  const float* feat_s = (const float*)d_in[0];
  const int*   y_s    = (const int*)d_in[1];
  const float* feat_q = (const float*)d_in[2];
  int* out = (int*)d_out;

  char* wp = (char*)d_ws;
  auto alloc = [&](size_t bytes) -> char* {
    char* p = wp;
    wp += (bytes + 255) & ~(size_t)255;
    return p;
  };
  float* Dq     = (float*)alloc((size_t)N_Q * N_Q * 4);      // 64 MB
  float* Pt     = (float*)alloc((size_t)DIM * N_C * 4);
  float* pn     = (float*)alloc(N_C * 4);
  float* qn     = (float*)alloc(N_Q * 4);
  float* aM     = (float*)alloc((size_t)N_Q * N_C * 4);
  float* d2min  = (float*)alloc(N_Q * 4);
  float* denom  = (float*)alloc(256);
  int*   nbr    = (int*)alloc((size_t)N_Q * KNN * 4);
  float* dnbr   = (float*)alloc((size_t)N_Q * KNN * 4);
  float* sigma  = (float*)alloc(N_Q * 4);
  float* wh     = (float*)alloc((size_t)N_Q * KNN * 4);
  float* rowsum = (float*)alloc(N_Q * 4);
  int*   indeg  = (int*)alloc(N_Q * 4);
  int*   rowptr = (int*)alloc((N_Q + 1) * 4);
  int*   fillc  = (int*)alloc(N_Q * 4);
  int*   colA   = (int*)alloc((size_t)2 * N_Q * KNN * 4);
  float* wA     = (float*)alloc((size_t)2 * N_Q * KNN * 4);
  float* buf0   = (float*)alloc((size_t)N_Q * N_C * 4);
  float* buf1   = (float*)alloc((size_t)N_Q * N_C * 4);
  float* deltas = (float*)alloc(64 * 4);
  float* coefA  = (float*)alloc(N_Q * 4);

  hipMemsetAsync(rowsum, 0, N_Q * 4, stream);
  hipMemsetAsync(indeg,  0, N_Q * 4, stream);
  hipMemsetAsync(fillc,  0, N_Q * 4, stream);
  hipMemsetAsync(deltas, 0, 64 * 4, stream);

  proto_kernel  <<<N_C, 256, 0, stream>>>(feat_s, y_s, Pt, pn);
  rownorm_kernel<<<N_Q, 256, 0, stream>>>(feat_q, qn);
  dist_gemm     <<<dim3(N_Q/128, N_Q/128), 256, 0, stream>>>(feat_q, qn, Dq);
  topk_kernel   <<<N_Q, 256, 0, stream>>>(Dq, nbr, dnbr, sigma);
  a_kernel      <<<N_Q, 64, 0, stream>>>(feat_q, Pt, qn, pn, aM, d2min);
  median_kernel <<<1, 1024, 0, stream>>>(d2min, denom);
  wdeg_kernel   <<<(N_Q*KNN + 255)/256, 256, 0, stream>>>(nbr, dnbr, sigma, wh, rowsum, indeg);
  scan_kernel   <<<1, 256, 0, stream>>>(indeg, rowptr);
  fill_kernel   <<<(N_Q*KNN + 255)/256, 256, 0, stream>>>(nbr, wh, rowptr, fillc, colA, wA);
  coef_kernel   <<<(N_Q + 255)/256, 256, 0, stream>>>(d2min, denom, rowsum, coefA);

  void* args[] = {&aM, &coefA, &rowptr, &colA, &wA, &buf0, &buf1, &deltas, &out};
  hipLaunchCooperativeKernel((void*)mm_loop, dim3(64), dim3(1024), args, 0, stream);
}